// Round 1
// baseline (2443.715 us; speedup 1.0000x reference)
//
#include <hip/hip_runtime.h>
#include <math.h>

#define NN 50000
#define IN_DIM 100
#define DD 128
#define HH 8
#define LL 3
#define GG 64
#define FFD 512
#define EE 800000
#define POOL_CHUNK 512

// ---------------------------------------------------------------------------
// Generic fp32 GEMM: C[n,M] = A[n,K] @ W[K,M] (+bias) (relu?) (+resid)
// 64x64 tile, BK=32, 256 threads, 4x4 register micro-tile per thread.
// ---------------------------------------------------------------------------
__global__ __launch_bounds__(256) void gemm_f32(
    const float* __restrict__ A, const float* __restrict__ W,
    const float* __restrict__ bias, const float* __restrict__ resid,
    float* __restrict__ C, int n, int K, int M, int do_relu)
{
    __shared__ float As[32][68];   // [k][m], padded to 68 for alignment
    __shared__ float Bs[32][64];   // [k][n]
    const int tid = threadIdx.x;
    const int bm = blockIdx.x * 64;
    const int bn = blockIdx.y * 64;
    const int tm = (tid >> 4) << 2;   // 0..60
    const int tn = (tid & 15) << 2;   // 0..60
    float acc[4][4] = {};

    for (int k0 = 0; k0 < K; k0 += 32) {
        // A tile: 64 rows x 32 k  (transposed into As[k][m])
#pragma unroll
        for (int i = 0; i < 8; ++i) {
            int lin = tid + i * 256;     // 0..2047
            int row = lin >> 5;
            int kc  = lin & 31;
            int gr = bm + row, gk = k0 + kc;
            float v = 0.f;
            if (gr < n && gk < K) v = A[(size_t)gr * K + gk];
            As[kc][row] = v;
        }
        // B tile: 32 k x 64 cols
#pragma unroll
        for (int i = 0; i < 8; ++i) {
            int lin = tid + i * 256;
            int kr = lin >> 6;
            int c  = lin & 63;
            int gk = k0 + kr;
            float v = 0.f;
            if (gk < K) v = W[(size_t)gk * M + bn + c];
            Bs[kr][c] = v;
        }
        __syncthreads();
#pragma unroll
        for (int kk = 0; kk < 32; ++kk) {
            float4 a4 = *(const float4*)&As[kk][tm];
            float4 b4 = *(const float4*)&Bs[kk][tn];
            float av[4] = {a4.x, a4.y, a4.z, a4.w};
            float bv[4] = {b4.x, b4.y, b4.z, b4.w};
#pragma unroll
            for (int i = 0; i < 4; ++i)
#pragma unroll
                for (int j = 0; j < 4; ++j)
                    acc[i][j] += av[i] * bv[j];
        }
        __syncthreads();
    }

#pragma unroll
    for (int i = 0; i < 4; ++i) {
        int row = bm + tm + i;
        if (row >= n) continue;
        size_t base = (size_t)row * M + bn + tn;
        float4 v = make_float4(acc[i][0], acc[i][1], acc[i][2], acc[i][3]);
        if (bias) {
            float4 b = *(const float4*)&bias[bn + tn];
            v.x += b.x; v.y += b.y; v.z += b.z; v.w += b.w;
        }
        if (do_relu) {
            v.x = fmaxf(v.x, 0.f); v.y = fmaxf(v.y, 0.f);
            v.z = fmaxf(v.z, 0.f); v.w = fmaxf(v.w, 0.f);
        }
        if (resid) {
            float4 r = *(const float4*)&resid[base];
            v.x += r.x; v.y += r.y; v.z += r.z; v.w += r.w;
        }
        *(float4*)&C[base] = v;
    }
}

// ---------------------------------------------------------------------------
// CSR-by-dst construction
// ---------------------------------------------------------------------------
__global__ void count_kernel(const int* __restrict__ dst, int* __restrict__ counts)
{
    int e = blockIdx.x * 256 + threadIdx.x;
    if (e < EE) atomicAdd(&counts[dst[e]], 1);
}

__global__ void scan_kernel(const int* __restrict__ counts, int* __restrict__ offsets, int n)
{
    __shared__ int buf[1024];
    __shared__ int carry;
    if (threadIdx.x == 0) { carry = 0; offsets[0] = 0; }
    __syncthreads();
    for (int base = 0; base < n; base += 1024) {
        int i = base + threadIdx.x;
        int v = (i < n) ? counts[i] : 0;
        buf[threadIdx.x] = v;
        __syncthreads();
        for (int off = 1; off < 1024; off <<= 1) {
            int t = (threadIdx.x >= off) ? buf[threadIdx.x - off] : 0;
            __syncthreads();
            buf[threadIdx.x] += t;
            __syncthreads();
        }
        int incl = buf[threadIdx.x] + carry;
        if (i < n) offsets[i + 1] = incl;
        __syncthreads();
        if (threadIdx.x == 1023) carry = incl;
        __syncthreads();
    }
}

__global__ void fill_kernel(const int* __restrict__ src, const int* __restrict__ dst,
                            const int* __restrict__ offsets, int* __restrict__ cursor,
                            int* __restrict__ csr_src)
{
    int e = blockIdx.x * 256 + threadIdx.x;
    if (e < EE) {
        int d = dst[e];
        int pos = atomicAdd(&cursor[d], 1);
        csr_src[offsets[d] + pos] = src[e];
    }
}

// ---------------------------------------------------------------------------
// Fused attention: one wave per dst node; 8 heads x 8 lanes (2 dims/lane).
// Online softmax over incoming edges; no score buffer, no atomics.
// ---------------------------------------------------------------------------
__global__ __launch_bounds__(256) void attn_kernel(
    const float* __restrict__ QK, const float* __restrict__ V,
    const int* __restrict__ offsets, const int* __restrict__ csr_src,
    float* __restrict__ attnout)
{
    int wave = threadIdx.x >> 6;
    int lane = threadIdx.x & 63;
    int node = blockIdx.x * 4 + wave;
    if (node >= NN) return;
    int qoff = ((lane >> 3) << 4) + ((lane & 7) << 1);  // head*16 + sub*2
    float2 kk = *(const float2*)&QK[(size_t)node * 256 + 128 + qoff];
    float m = -INFINITY, s = 0.f, a0 = 0.f, a1 = 0.f;
    int e = offsets[node], end = offsets[node + 1];
    for (; e < end; ++e) {
        int j = csr_src[e];
        float2 qj = *(const float2*)&QK[(size_t)j * 256 + qoff];
        float2 vj = *(const float2*)&V[(size_t)j * 128 + qoff];
        float p = kk.x * qj.x + kk.y * qj.y;
        p += __shfl_xor(p, 1, 64);
        p += __shfl_xor(p, 2, 64);
        p += __shfl_xor(p, 4, 64);
        float score = p * 0.25f;           // scale = hd^-0.5 = 16^-0.5
        float mn = fmaxf(m, score);
        float corr = __expf(m - mn);       // first edge: exp(-inf)=0
        float w = __expf(score - mn);
        s  = s  * corr + w;
        a0 = a0 * corr + w * vj.x;
        a1 = a1 * corr + w * vj.y;
        m = mn;
    }
    float inv = 1.f / (s + 1e-16f);        // no-edge nodes: 0 * 1e16 = 0
    *(float2*)&attnout[(size_t)node * 128 + qoff] = make_float2(a0 * inv, a1 * inv);
}

// ---------------------------------------------------------------------------
// Mean pool per graph (batch is sorted): run-length accumulate, flush on change
// ---------------------------------------------------------------------------
__global__ void pool_kernel(const float* __restrict__ h, const int* __restrict__ batch,
                            float* __restrict__ sums, int* __restrict__ cnts)
{
    int col = threadIdx.x;   // 128
    int start = blockIdx.x * POOL_CHUNK;
    int end = min(start + POOL_CHUNK, NN);
    float acc = 0.f;
    int cur = batch[start];
    int cnt = 0;
    for (int i = start; i < end; ++i) {
        int g = batch[i];
        if (g != cur) {
            atomicAdd(&sums[cur * DD + col], acc);
            if (col == 0) atomicAdd(&cnts[cur], cnt);
            acc = 0.f; cnt = 0; cur = g;
        }
        acc += h[(size_t)i * DD + col];
        ++cnt;
    }
    atomicAdd(&sums[cur * DD + col], acc);
    if (col == 0) atomicAdd(&cnts[cur], cnt);
}

__global__ void finalize_kernel(const float* __restrict__ sums, const int* __restrict__ cnts,
                                float* __restrict__ out)
{
    int g = blockIdx.x, c = threadIdx.x;
    out[g * DD + c] = sums[g * DD + c] / fmaxf((float)cnts[g], 1.f);
}

// ---------------------------------------------------------------------------
extern "C" void kernel_launch(void* const* d_in, const int* in_sizes, int n_in,
                              void* d_out, int out_size, void* d_ws, size_t ws_size,
                              hipStream_t stream)
{
    const float* x     = (const float*)d_in[0];
    const float* emb_W = (const float*)d_in[1];
    const float* Wqk   = (const float*)d_in[2];
    const float* Wv    = (const float*)d_in[3];
    const float* Wo    = (const float*)d_in[4];
    const float* bo    = (const float*)d_in[5];
    const float* W1    = (const float*)d_in[6];
    const float* b1    = (const float*)d_in[7];
    const float* W2    = (const float*)d_in[8];
    const float* b2    = (const float*)d_in[9];
    const int* eidx    = (const int*)d_in[10];
    const int* batch   = (const int*)d_in[11];
    float* out = (float*)d_out;

    // ws layout
    float* h       = (float*)d_ws;                    // N*128
    float* QK      = h + (size_t)NN * DD;             // N*256
    float* V       = QK + (size_t)NN * 2 * DD;        // N*128
    float* attnout = V + (size_t)NN * DD;             // N*128
    float* ffmid   = QK;                              // N*512, aliases QK|V|attnout
    int* counts  = (int*)(attnout + (size_t)NN * DD); // N+1
    int* offsets = counts + (NN + 1);                 // N+1
    int* cursor  = offsets + (NN + 1);                // N
    int* csr_src = cursor + NN;                       // E
    float* sums  = (float*)(csr_src + EE);            // G*128
    int* cnts    = (int*)(sums + GG * DD);            // G

    const int* src = eidx;
    const int* dst = eidx + EE;

    hipMemsetAsync(counts, 0, (NN + 1) * sizeof(int), stream);
    hipMemsetAsync(cursor, 0, NN * sizeof(int), stream);
    hipMemsetAsync(sums, 0, GG * DD * sizeof(float) + GG * sizeof(int), stream);

    // CSR build (once per call, reused by all 3 layers)
    count_kernel<<<dim3((EE + 255) / 256), dim3(256), 0, stream>>>(dst, counts);
    scan_kernel<<<dim3(1), dim3(1024), 0, stream>>>(counts, offsets, NN);
    fill_kernel<<<dim3((EE + 255) / 256), dim3(256), 0, stream>>>(src, dst, offsets, cursor, csr_src);

    dim3 blk(256);
    const int gx = (NN + 63) / 64;

    // embedding: h = x @ emb_W
    gemm_f32<<<dim3(gx, DD / 64), blk, 0, stream>>>(x, emb_W, nullptr, nullptr, h, NN, IN_DIM, DD, 0);

    for (int l = 0; l < LL; ++l) {
        gemm_f32<<<dim3(gx, (2 * DD) / 64), blk, 0, stream>>>(
            h, Wqk + (size_t)l * DD * 2 * DD, nullptr, nullptr, QK, NN, DD, 2 * DD, 0);
        gemm_f32<<<dim3(gx, DD / 64), blk, 0, stream>>>(
            h, Wv + (size_t)l * DD * DD, nullptr, nullptr, V, NN, DD, DD, 0);
        attn_kernel<<<dim3(NN / 4), blk, 0, stream>>>(QK, V, offsets, csr_src, attnout);
        // h = h + attnout @ Wo + bo   (in-place residual update)
        gemm_f32<<<dim3(gx, DD / 64), blk, 0, stream>>>(
            attnout, Wo + (size_t)l * DD * DD, bo + (size_t)l * DD, h, h, NN, DD, DD, 0);
        // ffmid = relu(h @ W1 + b1)
        gemm_f32<<<dim3(gx, FFD / 64), blk, 0, stream>>>(
            h, W1 + (size_t)l * DD * FFD, b1 + (size_t)l * FFD, nullptr, ffmid, NN, DD, FFD, 1);
        // h = h + ffmid @ W2 + b2
        gemm_f32<<<dim3(gx, DD / 64), blk, 0, stream>>>(
            ffmid, W2 + (size_t)l * FFD * DD, b2 + (size_t)l * DD, h, h, NN, FFD, DD, 0);
    }

    pool_kernel<<<dim3((NN + POOL_CHUNK - 1) / POOL_CHUNK), dim3(128), 0, stream>>>(h, batch, sums, cnts);
    finalize_kernel<<<dim3(GG), dim3(128), 0, stream>>>(sums, cnts, out);
}

// Round 2
// 1789.144 us; speedup vs baseline: 1.3659x; 1.3659x over previous
//
#include <hip/hip_runtime.h>
#include <math.h>

#define NN 50000
#define NPAD 50048           // 391*128
#define IN_DIM 100
#define DD 128
#define HH 8
#define LL 3
#define GG 64
#define FFD 512
#define EE 800000
#define POOL_CHUNK 512

typedef __attribute__((ext_vector_type(8))) short bf8_t;   // 8 bf16 (4 VGPRs)
typedef __attribute__((ext_vector_type(4))) float f4_t;    // 4 fp32 acc

static __device__ __forceinline__ unsigned short f2bf(float f) {
    unsigned u = __builtin_bit_cast(unsigned, f);
    unsigned r = (u + 0x7FFFu + ((u >> 16) & 1u)) >> 16;
    return (unsigned short)r;
}
static __device__ __forceinline__ float bf2f(unsigned short b) {
    unsigned u = ((unsigned)b) << 16;
    return __builtin_bit_cast(float, u);
}

#define GLD16(gsrc, ldst) __builtin_amdgcn_global_load_lds( \
    (const __attribute__((address_space(1))) unsigned int*)(gsrc), \
    (__attribute__((address_space(3))) unsigned int*)(ldst), 16, 0, 0)

// ---------------------------------------------------------------------------
// Split-bf16 MFMA GEMM: C[n,M] = A[n,K] @ W[K,M] via hi/lo decomposition.
// Ac: [n][nk][2][32] bf16 (hi chunk, lo chunk per 32-k block)
// Bc: [M][nk][2][32] bf16 (W transposed + split, same layout)
// 128x128 tile, BK=32, 256 thr = 4 waves (2x2), 16x16x32 MFMA, 3 mfma/frag.
// LDS: linear dest for global_load_lds, source pre-swizzled, reads XOR-swz.
// ---------------------------------------------------------------------------
__global__ __launch_bounds__(256) void mfma_gemm(
    const unsigned short* __restrict__ Ac,
    const unsigned short* __restrict__ Bc,
    const float* __restrict__ bias,
    const float* __restrict__ resid,
    float* __restrict__ Cf,              // optional fp32 out
    unsigned short* __restrict__ Chl,    // optional bf16 hi/lo out [n][M/32][2][32]
    int n, int nk, int M, int do_relu)
{
    __shared__ unsigned short ldsA[128 * 64];   // 128 rows x 128B (hi|lo), 16KB
    __shared__ unsigned short ldsB[128 * 64];
    const int tid = threadIdx.x;
    const int lane = tid & 63;
    const int wid = tid >> 6;
    const int wr = (wid >> 1) * 64;
    const int wc = (wid & 1) * 64;
    const long brow = (long)blockIdx.x * 128;
    const long bcol = (long)blockIdx.y * 128;

    f4_t acc[4][4] = {};

    // staging: thread t, issue i -> linear LDS byte (i*256+t)*16
    const int srow = tid >> 3;              // row within 32-row group
    const int kbg = (((tid & 7) << 4) ^ ((srow & 7) << 4)) >> 1;  // src elem offset

    for (int kc = 0; kc < nk; ++kc) {
#pragma unroll
        for (int i = 0; i < 4; ++i) {
            int row = i * 32 + srow;
            const unsigned short* sA = Ac + ((brow + row) * (size_t)nk + kc) * 64 + kbg;
            GLD16(sA, &ldsA[((size_t)i * 256 + tid) * 8]);
            const unsigned short* sB = Bc + ((bcol + row) * (size_t)nk + kc) * 64 + kbg;
            GLD16(sB, &ldsB[((size_t)i * 256 + tid) * 8]);
        }
        __syncthreads();

        bf8_t ah[4], al[4], bh[4], bl[4];
        const int fr = lane & 15;
        const int kq = (lane >> 4) << 4;    // k-group byte offset 0/16/32/48
#pragma unroll
        for (int m = 0; m < 4; ++m) {
            int row = wr + m * 16 + fr;
            int sw = (row & 7) << 4;
            ah[m] = *(const bf8_t*)&ldsA[row * 64 + ((kq ^ sw) >> 1)];
            al[m] = *(const bf8_t*)&ldsA[row * 64 + (((kq + 64) ^ sw) >> 1)];
        }
#pragma unroll
        for (int nn = 0; nn < 4; ++nn) {
            int row = wc + nn * 16 + fr;
            int sw = (row & 7) << 4;
            bh[nn] = *(const bf8_t*)&ldsB[row * 64 + ((kq ^ sw) >> 1)];
            bl[nn] = *(const bf8_t*)&ldsB[row * 64 + (((kq + 64) ^ sw) >> 1)];
        }
#pragma unroll
        for (int m = 0; m < 4; ++m)
#pragma unroll
            for (int nn = 0; nn < 4; ++nn) {
                acc[m][nn] = __builtin_amdgcn_mfma_f32_16x16x32_bf16(ah[m], bh[nn], acc[m][nn], 0, 0, 0);
                acc[m][nn] = __builtin_amdgcn_mfma_f32_16x16x32_bf16(al[m], bh[nn], acc[m][nn], 0, 0, 0);
                acc[m][nn] = __builtin_amdgcn_mfma_f32_16x16x32_bf16(ah[m], bl[nn], acc[m][nn], 0, 0, 0);
            }
        __syncthreads();
    }

    // epilogue: C/D layout col=lane&15, row=(lane>>4)*4+i
    const int efr = lane & 15, efq = lane >> 4;
#pragma unroll
    for (int m = 0; m < 4; ++m) {
#pragma unroll
        for (int i = 0; i < 4; ++i) {
            long row = brow + wr + m * 16 + efq * 4 + i;
            if (row >= n) continue;
#pragma unroll
            for (int nn = 0; nn < 4; ++nn) {
                int col = (int)bcol + wc + nn * 16 + efr;
                float v = acc[m][nn][i];
                if (bias) v += bias[col];
                if (do_relu) v = fmaxf(v, 0.f);
                if (resid) v += resid[row * M + col];
                if (Cf) Cf[row * M + col] = v;
                if (Chl) {
                    unsigned short hb = f2bf(v);
                    float lo = v - bf2f(hb);
                    size_t cb = (row * (size_t)(M >> 5) + (col >> 5)) * 64 + (col & 31);
                    Chl[cb] = hb;
                    Chl[cb + 32] = f2bf(lo);
                }
            }
        }
    }
}

// ---------------------------------------------------------------------------
// x [n,100] fp32 -> xc [n][4][2][32] bf16 hi/lo, zero-padded to K=128
// ---------------------------------------------------------------------------
__global__ void cvt_x_kernel(const float* __restrict__ x, unsigned short* __restrict__ xc)
{
    int idx = blockIdx.x * 256 + threadIdx.x;
    if (idx >= NN * 128) return;
    int node = idx >> 7, col = idx & 127;
    float v = (col < IN_DIM) ? x[(size_t)node * IN_DIM + col] : 0.f;
    unsigned short hb = f2bf(v);
    float lo = v - bf2f(hb);
    size_t b = (size_t)node * 256 + (col >> 5) * 64 + (col & 31);
    xc[b] = hb;
    xc[b + 32] = f2bf(lo);
}

// ---------------------------------------------------------------------------
// W [K,M] fp32 -> Wt [M][nkpad][2][32] bf16 hi/lo (transpose + split + k-pad)
// ---------------------------------------------------------------------------
__global__ void wcvt_kernel(const float* __restrict__ W, unsigned short* __restrict__ Wt,
                            int K, int nkpad, int M)
{
    int idx = blockIdx.x * 256 + threadIdx.x;
    if (idx >= M * nkpad) return;
    int m = idx % M;
    int kc = idx / M;
    size_t ob = ((size_t)m * nkpad + kc) * 64;
    for (int i = 0; i < 32; ++i) {
        int k = kc * 32 + i;
        float v = (k < K) ? W[(size_t)k * M + m] : 0.f;
        unsigned short hb = f2bf(v);
        Wt[ob + i] = hb;
        Wt[ob + 32 + i] = f2bf(v - bf2f(hb));
    }
}

// ---------------------------------------------------------------------------
// CSR-by-dst construction
// ---------------------------------------------------------------------------
__global__ void count_kernel(const int* __restrict__ dst, int* __restrict__ counts)
{
    int e = blockIdx.x * 256 + threadIdx.x;
    if (e < EE) atomicAdd(&counts[dst[e]], 1);
}

__global__ void scan_kernel(const int* __restrict__ counts, int* __restrict__ offsets, int n)
{
    __shared__ int buf[1024];
    __shared__ int carry;
    if (threadIdx.x == 0) { carry = 0; offsets[0] = 0; }
    __syncthreads();
    for (int base = 0; base < n; base += 1024) {
        int i = base + threadIdx.x;
        int v = (i < n) ? counts[i] : 0;
        buf[threadIdx.x] = v;
        __syncthreads();
        for (int off = 1; off < 1024; off <<= 1) {
            int t = (threadIdx.x >= off) ? buf[threadIdx.x - off] : 0;
            __syncthreads();
            buf[threadIdx.x] += t;
            __syncthreads();
        }
        int incl = buf[threadIdx.x] + carry;
        if (i < n) offsets[i + 1] = incl;
        __syncthreads();
        if (threadIdx.x == 1023) carry = incl;
        __syncthreads();
    }
}

__global__ void fill_kernel(const int* __restrict__ src, const int* __restrict__ dst,
                            const int* __restrict__ offsets, int* __restrict__ cursor,
                            int* __restrict__ csr_src)
{
    int e = blockIdx.x * 256 + threadIdx.x;
    if (e < EE) {
        int d = dst[e];
        int pos = atomicAdd(&cursor[d], 1);
        csr_src[offsets[d] + pos] = src[e];
    }
}

// ---------------------------------------------------------------------------
// Fused attention: one wave per dst node; 8 heads x 8 lanes (2 dims/lane).
// Online softmax; writes bf16 hi/lo pairs directly (feeds Wo GEMM).
// ---------------------------------------------------------------------------
__global__ __launch_bounds__(256) void attn_kernel(
    const float* __restrict__ QK, const float* __restrict__ V,
    const int* __restrict__ offsets, const int* __restrict__ csr_src,
    unsigned short* __restrict__ ac)    // [n][4][2][32]
{
    int wave = threadIdx.x >> 6;
    int lane = threadIdx.x & 63;
    int node = blockIdx.x * 4 + wave;
    if (node >= NN) return;
    int qoff = ((lane >> 3) << 4) + ((lane & 7) << 1);  // head*16 + sub*2
    float2 kk = *(const float2*)&QK[(size_t)node * 256 + 128 + qoff];
    float m = -INFINITY, s = 0.f, a0 = 0.f, a1 = 0.f;
    int e = offsets[node], end = offsets[node + 1];
    for (; e < end; ++e) {
        int j = csr_src[e];
        float2 qj = *(const float2*)&QK[(size_t)j * 256 + qoff];
        float2 vj = *(const float2*)&V[(size_t)j * 128 + qoff];
        float p = kk.x * qj.x + kk.y * qj.y;
        p += __shfl_xor(p, 1, 64);
        p += __shfl_xor(p, 2, 64);
        p += __shfl_xor(p, 4, 64);
        float score = p * 0.25f;
        float mn = fmaxf(m, score);
        float corr = __expf(m - mn);
        float w = __expf(score - mn);
        s  = s  * corr + w;
        a0 = a0 * corr + w * vj.x;
        a1 = a1 * corr + w * vj.y;
        m = mn;
    }
    float inv = 1.f / (s + 1e-16f);
    float o0 = a0 * inv, o1 = a1 * inv;
    int chunk = qoff >> 5, pos = qoff & 31;
    size_t b = ((size_t)node * 4 + chunk) * 64 + pos;
    unsigned short h0 = f2bf(o0), h1 = f2bf(o1);
    ac[b] = h0;       ac[b + 1] = h1;
    ac[b + 32] = f2bf(o0 - bf2f(h0));
    ac[b + 33] = f2bf(o1 - bf2f(h1));
}

// ---------------------------------------------------------------------------
// Mean pool per graph (batch sorted)
// ---------------------------------------------------------------------------
__global__ void pool_kernel(const float* __restrict__ h, const int* __restrict__ batch,
                            float* __restrict__ sums, int* __restrict__ cnts)
{
    int col = threadIdx.x;
    int start = blockIdx.x * POOL_CHUNK;
    int end = min(start + POOL_CHUNK, NN);
    float acc = 0.f;
    int cur = batch[start];
    int cnt = 0;
    for (int i = start; i < end; ++i) {
        int g = batch[i];
        if (g != cur) {
            atomicAdd(&sums[cur * DD + col], acc);
            if (col == 0) atomicAdd(&cnts[cur], cnt);
            acc = 0.f; cnt = 0; cur = g;
        }
        acc += h[(size_t)i * DD + col];
        ++cnt;
    }
    atomicAdd(&sums[cur * DD + col], acc);
    if (col == 0) atomicAdd(&cnts[cur], cnt);
}

__global__ void finalize_kernel(const float* __restrict__ sums, const int* __restrict__ cnts,
                                float* __restrict__ out)
{
    int g = blockIdx.x, c = threadIdx.x;
    out[g * DD + c] = sums[g * DD + c] / fmaxf((float)cnts[g], 1.f);
}

// ---------------------------------------------------------------------------
extern "C" void kernel_launch(void* const* d_in, const int* in_sizes, int n_in,
                              void* d_out, int out_size, void* d_ws, size_t ws_size,
                              hipStream_t stream)
{
    const float* x     = (const float*)d_in[0];
    const float* emb_W = (const float*)d_in[1];
    const float* Wqk   = (const float*)d_in[2];
    const float* Wv    = (const float*)d_in[3];
    const float* Wo    = (const float*)d_in[4];
    const float* bo    = (const float*)d_in[5];
    const float* W1    = (const float*)d_in[6];
    const float* b1    = (const float*)d_in[7];
    const float* W2    = (const float*)d_in[8];
    const float* b2    = (const float*)d_in[9];
    const int* eidx    = (const int*)d_in[10];
    const int* batch   = (const int*)d_in[11];
    float* out = (float*)d_out;

    // ---- ws layout (bytes, 256-aligned) ----
    char* base = (char*)d_ws;
    size_t off = 0;
    auto alloc = [&](size_t bytes) { char* p = base + off; off = (off + bytes + 255) & ~(size_t)255; return p; };

    float*          h    = (float*)alloc((size_t)NPAD * DD * 4);                 // 25.6MB
    unsigned short* hc   = (unsigned short*)alloc((size_t)NPAD * 2 * DD * 2);    // 25.6MB
    char*           regB = alloc((size_t)NPAD * 2 * FFD * 2);                    // 102.5MB (fc-size)
    float*          QK   = (float*)regB;                                         // 50000*256 f32
    float*          V    = (float*)(regB + (size_t)NN * 256 * 4);                // 50000*128 f32
    unsigned short* ac   = (unsigned short*)(regB + (size_t)NN * 256 * 4 + (size_t)NN * 128 * 4);
    unsigned short* fc   = (unsigned short*)regB;                                // [NPAD][16][2][32]
    unsigned short* xc   = (unsigned short*)regB;                                // [NPAD][4][2][32]

    unsigned short* embT = (unsigned short*)alloc((size_t)DD * 4 * 64 * 2);
    unsigned short* WqkT = (unsigned short*)alloc((size_t)LL * 256 * 4 * 64 * 2);
    unsigned short* WvT  = (unsigned short*)alloc((size_t)LL * 128 * 4 * 64 * 2);
    unsigned short* WoT  = (unsigned short*)alloc((size_t)LL * 128 * 4 * 64 * 2);
    unsigned short* W1T  = (unsigned short*)alloc((size_t)LL * 512 * 4 * 64 * 2);
    unsigned short* W2T  = (unsigned short*)alloc((size_t)LL * 128 * 16 * 64 * 2);

    int* counts  = (int*)alloc((NN + 1) * 4);
    int* offsets = (int*)alloc((NN + 1) * 4);
    int* cursor  = (int*)alloc(NN * 4);
    int* csr_src = (int*)alloc((size_t)EE * 4);
    float* sums  = (float*)alloc(GG * DD * 4 + GG * 4);
    int* cnts    = (int*)(sums + GG * DD);

    const int* src = eidx;
    const int* dst = eidx + EE;

    hipMemsetAsync(counts, 0, (NN + 1) * sizeof(int), stream);
    hipMemsetAsync(cursor, 0, NN * sizeof(int), stream);
    hipMemsetAsync(sums, 0, GG * DD * sizeof(float) + GG * sizeof(int), stream);

    // CSR build
    count_kernel<<<dim3((EE + 255) / 256), dim3(256), 0, stream>>>(dst, counts);
    scan_kernel<<<dim3(1), dim3(1024), 0, stream>>>(counts, offsets, NN);
    fill_kernel<<<dim3((EE + 255) / 256), dim3(256), 0, stream>>>(src, dst, offsets, cursor, csr_src);

    // weight transpose + hi/lo split
    auto wc_launch = [&](const float* W, unsigned short* Wt, int K, int nkpad, int M) {
        int tot = M * nkpad;
        wcvt_kernel<<<dim3((tot + 255) / 256), dim3(256), 0, stream>>>(W, Wt, K, nkpad, M);
    };
    wc_launch(emb_W, embT, IN_DIM, 4, DD);
    for (int l = 0; l < LL; ++l) {
        wc_launch(Wqk + (size_t)l * DD * 256, WqkT + (size_t)l * 256 * 256, DD, 4, 256);
        wc_launch(Wv  + (size_t)l * DD * DD,  WvT  + (size_t)l * 128 * 256, DD, 4, 128);
        wc_launch(Wo  + (size_t)l * DD * DD,  WoT  + (size_t)l * 128 * 256, DD, 4, 128);
        wc_launch(W1  + (size_t)l * DD * FFD, W1T  + (size_t)l * 512 * 256, DD, 4, 512);
        wc_launch(W2  + (size_t)l * FFD * DD, W2T  + (size_t)l * 128 * 1024, FFD, 16, 128);
    }

    // x -> xc
    cvt_x_kernel<<<dim3((NN * 128 + 255) / 256), dim3(256), 0, stream>>>(x, xc);

    dim3 blk(256);
    const int gx = (NN + 127) / 128;   // 391

    // emb: h = x @ emb_W   (also emit hc)
    mfma_gemm<<<dim3(gx, 1), blk, 0, stream>>>(xc, embT, nullptr, nullptr, h, hc, NN, 4, DD, 0);

    for (int l = 0; l < LL; ++l) {
        // QK = h @ Wqk[l]
        mfma_gemm<<<dim3(gx, 2), blk, 0, stream>>>(
            hc, WqkT + (size_t)l * 256 * 256, nullptr, nullptr, QK, nullptr, NN, 4, 256, 0);
        // V = h @ Wv[l]
        mfma_gemm<<<dim3(gx, 1), blk, 0, stream>>>(
            hc, WvT + (size_t)l * 128 * 256, nullptr, nullptr, V, nullptr, NN, 4, 128, 0);
        // attention -> ac (bf16 hi/lo)
        attn_kernel<<<dim3(NN / 4), blk, 0, stream>>>(QK, V, offsets, csr_src, ac);
        // h = h + ac @ Wo + bo; also emit hc
        mfma_gemm<<<dim3(gx, 1), blk, 0, stream>>>(
            ac, WoT + (size_t)l * 128 * 256, bo + (size_t)l * DD, h, h, hc, NN, 4, 128, 0);
        // fc = relu(h @ W1 + b1)  (bf16-pair only)
        mfma_gemm<<<dim3(gx, 4), blk, 0, stream>>>(
            hc, W1T + (size_t)l * 512 * 256, b1 + (size_t)l * FFD, nullptr, nullptr, fc, NN, 4, 512, 1);
        // h = h + fc @ W2 + b2; also emit hc for next layer
        mfma_gemm<<<dim3(gx, 1), blk, 0, stream>>>(
            fc, W2T + (size_t)l * 128 * 1024, b2 + (size_t)l * DD, h, h, hc, NN, 16, 128, 0);
    }

    pool_kernel<<<dim3((NN + POOL_CHUNK - 1) / POOL_CHUNK), dim3(128), 0, stream>>>(h, batch, sums, cnts);
    finalize_kernel<<<dim3(GG), dim3(128), 0, stream>>>(sums, cnts, out);
}

// Round 4
// 1117.251 us; speedup vs baseline: 2.1873x; 1.6014x over previous
//
#include <hip/hip_runtime.h>
#include <math.h>

#define NN 50000
#define NPAD 50048           // 391*128
#define IN_DIM 100
#define DD 128
#define HH 8
#define LL 3
#define GG 64
#define FFD 512
#define EE 800000

typedef __attribute__((ext_vector_type(8))) short bf8_t;   // 8 bf16 (4 VGPRs)
typedef __attribute__((ext_vector_type(4))) float f4_t;    // 4 fp32 acc

static __device__ __forceinline__ unsigned short f2bf(float f) {
    unsigned u = __builtin_bit_cast(unsigned, f);
    unsigned r = (u + 0x7FFFu + ((u >> 16) & 1u)) >> 16;
    return (unsigned short)r;
}
static __device__ __forceinline__ float bf2f(unsigned short b) {
    unsigned u = ((unsigned)b) << 16;
    return __builtin_bit_cast(float, u);
}

#define GLD16(gsrc, ldst) __builtin_amdgcn_global_load_lds( \
    (const __attribute__((address_space(1))) unsigned int*)(gsrc), \
    (__attribute__((address_space(3))) unsigned int*)(ldst), 16, 0, 0)

// ---------------------------------------------------------------------------
// Split-bf16 MFMA GEMM: C[n,M] = A[n,K] @ W[K,M] via hi/lo decomposition.
// Ac: [n][nk][2][32] bf16 (hi chunk, lo chunk per 32-k block)
// Bc: [M][nk][2][32] bf16 (W transposed + split, same layout)
// 128x128 tile, BK=32, 4 waves (2x2), 16x16x32 MFMA, 3 mfma/frag (Markidis).
// ---------------------------------------------------------------------------
__global__ __launch_bounds__(256) void mfma_gemm(
    const unsigned short* __restrict__ Ac,
    const unsigned short* __restrict__ Bc,
    const float* __restrict__ bias,
    const float* __restrict__ resid,
    float* __restrict__ Cf,
    unsigned short* __restrict__ Chl,
    unsigned short* __restrict__ Cb,
    int n, int nk, int M, int do_relu)
{
    __shared__ unsigned short ldsA[128 * 64];
    __shared__ unsigned short ldsB[128 * 64];
    const int tid = threadIdx.x;
    const int lane = tid & 63;
    const int wid = tid >> 6;
    const int wr = (wid >> 1) * 64;
    const int wc = (wid & 1) * 64;
    const long brow = (long)blockIdx.x * 128;
    const long bcol = (long)blockIdx.y * 128;

    f4_t acc[4][4] = {};

    const int srow = tid >> 3;
    const int kbg = (((tid & 7) << 4) ^ ((srow & 7) << 4)) >> 1;

    for (int kc = 0; kc < nk; ++kc) {
#pragma unroll
        for (int i = 0; i < 4; ++i) {
            int row = i * 32 + srow;
            const unsigned short* sA = Ac + ((brow + row) * (size_t)nk + kc) * 64 + kbg;
            GLD16(sA, &ldsA[((size_t)i * 256 + tid) * 8]);
            const unsigned short* sB = Bc + ((bcol + row) * (size_t)nk + kc) * 64 + kbg;
            GLD16(sB, &ldsB[((size_t)i * 256 + tid) * 8]);
        }
        __syncthreads();

        bf8_t ah[4], al[4], bh[4], bl[4];
        const int fr = lane & 15;
        const int kq = (lane >> 4) << 4;
#pragma unroll
        for (int m = 0; m < 4; ++m) {
            int row = wr + m * 16 + fr;
            int sw = (row & 7) << 4;
            ah[m] = *(const bf8_t*)&ldsA[row * 64 + ((kq ^ sw) >> 1)];
            al[m] = *(const bf8_t*)&ldsA[row * 64 + (((kq + 64) ^ sw) >> 1)];
        }
#pragma unroll
        for (int nn = 0; nn < 4; ++nn) {
            int row = wc + nn * 16 + fr;
            int sw = (row & 7) << 4;
            bh[nn] = *(const bf8_t*)&ldsB[row * 64 + ((kq ^ sw) >> 1)];
            bl[nn] = *(const bf8_t*)&ldsB[row * 64 + (((kq + 64) ^ sw) >> 1)];
        }
#pragma unroll
        for (int m = 0; m < 4; ++m)
#pragma unroll
            for (int nn = 0; nn < 4; ++nn) {
                acc[m][nn] = __builtin_amdgcn_mfma_f32_16x16x32_bf16(ah[m], bh[nn], acc[m][nn], 0, 0, 0);
                acc[m][nn] = __builtin_amdgcn_mfma_f32_16x16x32_bf16(al[m], bh[nn], acc[m][nn], 0, 0, 0);
                acc[m][nn] = __builtin_amdgcn_mfma_f32_16x16x32_bf16(ah[m], bl[nn], acc[m][nn], 0, 0, 0);
            }
        __syncthreads();
    }

    const int efr = lane & 15, efq = lane >> 4;
#pragma unroll
    for (int m = 0; m < 4; ++m) {
#pragma unroll
        for (int i = 0; i < 4; ++i) {
            long row = brow + wr + m * 16 + efq * 4 + i;
            if (row >= n) continue;
#pragma unroll
            for (int nn = 0; nn < 4; ++nn) {
                int col = (int)bcol + wc + nn * 16 + efr;
                float v = acc[m][nn][i];
                if (bias) v += bias[col];
                if (do_relu) v = fmaxf(v, 0.f);
                if (resid) v += resid[row * M + col];
                if (Cf) Cf[row * M + col] = v;
                if (Cb) Cb[row * M + col] = f2bf(v);
                if (Chl) {
                    unsigned short hb = f2bf(v);
                    float lo = v - bf2f(hb);
                    size_t cb = (row * (size_t)(M >> 5) + (col >> 5)) * 64 + (col & 31);
                    Chl[cb] = hb;
                    Chl[cb + 32] = f2bf(lo);
                }
            }
        }
    }
}

__global__ void cvt_x_kernel(const float* __restrict__ x, unsigned short* __restrict__ xc)
{
    int idx = blockIdx.x * 256 + threadIdx.x;
    if (idx >= NN * 128) return;
    int node = idx >> 7, col = idx & 127;
    float v = (col < IN_DIM) ? x[(size_t)node * IN_DIM + col] : 0.f;
    unsigned short hb = f2bf(v);
    float lo = v - bf2f(hb);
    size_t b = (size_t)node * 256 + (col >> 5) * 64 + (col & 31);
    xc[b] = hb;
    xc[b + 32] = f2bf(lo);
}

// 16 weight matrices: 1 emb + (Wqk, Wv, Wo, W1, W2) x 3 layers
struct WDesc { const float* W; unsigned short* Wt; int K, nkpad, M, base; };
struct WDescs { WDesc d[16]; int n; int total; };

__global__ void wcvt_all_kernel(WDescs ds)
{
    int idx = blockIdx.x * 256 + threadIdx.x;
    if (idx >= ds.total) return;
    int di = 0;
    while (di + 1 < ds.n && idx >= ds.d[di + 1].base) ++di;
    WDesc w = ds.d[di];
    int loc = idx - w.base;
    int m = loc % w.M;
    int kc = loc / w.M;
    size_t ob = ((size_t)m * w.nkpad + kc) * 64;
    for (int i = 0; i < 32; ++i) {
        int k = kc * 32 + i;
        float v = (k < w.K) ? w.W[(size_t)k * w.M + m] : 0.f;
        unsigned short hb = f2bf(v);
        w.Wt[ob + i] = hb;
        w.Wt[ob + 32 + i] = f2bf(v - bf2f(hb));
    }
}

__global__ void count_kernel(const int* __restrict__ dst, int* __restrict__ counts)
{
    int e = blockIdx.x * 256 + threadIdx.x;
    if (e < EE) atomicAdd(&counts[dst[e]], 1);
}

__global__ __launch_bounds__(1024) void scan1_kernel(
    const int* __restrict__ counts, int* __restrict__ offsets, int* __restrict__ bsums)
{
    __shared__ int buf[1024];
    int tid = threadIdx.x;
    int i = blockIdx.x * 1024 + tid;
    int v = (i < NN) ? counts[i] : 0;
    buf[tid] = v;
    __syncthreads();
    for (int off = 1; off < 1024; off <<= 1) {
        int t = (tid >= off) ? buf[tid - off] : 0;
        __syncthreads();
        buf[tid] += t;
        __syncthreads();
    }
    if (i < NN) offsets[i + 1] = buf[tid];
    if (tid == 1023) bsums[blockIdx.x] = buf[1023];
}

__global__ void scan2_kernel(int* __restrict__ bsums, int nb)
{
    __shared__ int buf[64];
    int tid = threadIdx.x;
    int v = (tid < nb) ? bsums[tid] : 0;
    buf[tid] = v;
    __syncthreads();
    for (int off = 1; off < 64; off <<= 1) {
        int t = (tid >= off) ? buf[tid - off] : 0;
        __syncthreads();
        buf[tid] += t;
        __syncthreads();
    }
    if (tid < nb) bsums[tid] = buf[tid] - v;   // exclusive
}

__global__ __launch_bounds__(1024) void scan3_kernel(
    int* __restrict__ offsets, const int* __restrict__ bsums)
{
    int i = blockIdx.x * 1024 + threadIdx.x;
    if (i < NN) offsets[i + 1] += bsums[blockIdx.x];
    if (i == 0) offsets[0] = 0;
}

__global__ void fill_kernel(const int* __restrict__ src, const int* __restrict__ dst,
                            const int* __restrict__ offsets, int* __restrict__ cursor,
                            int* __restrict__ csr_src)
{
    int e = blockIdx.x * 256 + threadIdx.x;
    if (e < EE) {
        int d = dst[e];
        int pos = atomicAdd(&cursor[d], 1);
        csr_src[offsets[d] + pos] = src[e];
    }
}

// ---------------------------------------------------------------------------
// Fused attention: one wave per dst node; 8 heads x 8 lanes (2 dims/lane).
// QKV plain bf16 [n][384] (q|k|v). Online softmax, 2-edge unrolled.
// ---------------------------------------------------------------------------
__global__ __launch_bounds__(256) void attn_kernel(
    const unsigned short* __restrict__ QKV,
    const int* __restrict__ offsets, const int* __restrict__ csr_src,
    unsigned short* __restrict__ ac)    // [n][4][2][32] hi/lo
{
    int wave = threadIdx.x >> 6;
    int lane = threadIdx.x & 63;
    int node = blockIdx.x * 4 + wave;
    if (node >= NN) return;
    int qoff = ((lane >> 3) << 4) + ((lane & 7) << 1);
    ushort2 k2 = *(const ushort2*)&QKV[(size_t)node * 384 + 128 + qoff];
    float kx = bf2f(k2.x), ky = bf2f(k2.y);
    float m = -INFINITY, s = 0.f, a0 = 0.f, a1 = 0.f;
    int e = offsets[node], end = offsets[node + 1];
    for (; e + 1 < end; e += 2) {
        int j0 = csr_src[e], j1 = csr_src[e + 1];
        ushort2 q0 = *(const ushort2*)&QKV[(size_t)j0 * 384 + qoff];
        ushort2 v0 = *(const ushort2*)&QKV[(size_t)j0 * 384 + 256 + qoff];
        ushort2 q1 = *(const ushort2*)&QKV[(size_t)j1 * 384 + qoff];
        ushort2 v1 = *(const ushort2*)&QKV[(size_t)j1 * 384 + 256 + qoff];
        float p0 = kx * bf2f(q0.x) + ky * bf2f(q0.y);
        float p1 = kx * bf2f(q1.x) + ky * bf2f(q1.y);
        p0 += __shfl_xor(p0, 1, 64);
        p0 += __shfl_xor(p0, 2, 64);
        p0 += __shfl_xor(p0, 4, 64);
        p1 += __shfl_xor(p1, 1, 64);
        p1 += __shfl_xor(p1, 2, 64);
        p1 += __shfl_xor(p1, 4, 64);
        float sc0 = p0 * 0.25f, sc1 = p1 * 0.25f;
        float mn = fmaxf(m, fmaxf(sc0, sc1));
        float corr = __expf(m - mn);
        float w0 = __expf(sc0 - mn), w1 = __expf(sc1 - mn);
        s  = s  * corr + w0 + w1;
        a0 = a0 * corr + w0 * bf2f(v0.x) + w1 * bf2f(v1.x);
        a1 = a1 * corr + w0 * bf2f(v0.y) + w1 * bf2f(v1.y);
        m = mn;
    }
    if (e < end) {
        int j = csr_src[e];
        ushort2 qj = *(const ushort2*)&QKV[(size_t)j * 384 + qoff];
        ushort2 vj = *(const ushort2*)&QKV[(size_t)j * 384 + 256 + qoff];
        float p = kx * bf2f(qj.x) + ky * bf2f(qj.y);
        p += __shfl_xor(p, 1, 64);
        p += __shfl_xor(p, 2, 64);
        p += __shfl_xor(p, 4, 64);
        float score = p * 0.25f;
        float mn = fmaxf(m, score);
        float corr = __expf(m - mn);
        float w = __expf(score - mn);
        s  = s  * corr + w;
        a0 = a0 * corr + w * bf2f(vj.x);
        a1 = a1 * corr + w * bf2f(vj.y);
        m = mn;
    }
    float inv = 1.f / (s + 1e-16f);
    float o0 = a0 * inv, o1 = a1 * inv;
    int chunk = qoff >> 5, pos = qoff & 31;
    size_t b = ((size_t)node * 4 + chunk) * 64 + pos;
    unsigned short h0 = f2bf(o0), h1 = f2bf(o1);
    ac[b] = h0;       ac[b + 1] = h1;
    ac[b + 32] = f2bf(o0 - bf2f(h0));
    ac[b + 33] = f2bf(o1 - bf2f(h1));
}

// ---------------------------------------------------------------------------
// Mean pool per graph: 256 rows/block striped 8 ways, float4 cols
// ---------------------------------------------------------------------------
__global__ __launch_bounds__(256) void pool_kernel(
    const float* __restrict__ h, const int* __restrict__ batch,
    float* __restrict__ sums, int* __restrict__ cnts)
{
    int tid = threadIdx.x;
    int c4 = tid & 31;
    int rs = tid >> 5;
    int start = blockIdx.x * 256;
    int r0 = start + rs;
    if (r0 >= NN) return;
    int lim = min(start + 256, NN);
    float4 acc = make_float4(0.f, 0.f, 0.f, 0.f);
    int cnt = 0;
    int cur = batch[r0];
    for (int r = r0; r < lim; r += 8) {
        int g = batch[r];
        if (g != cur) {
            atomicAdd(&sums[cur * DD + c4 * 4 + 0], acc.x);
            atomicAdd(&sums[cur * DD + c4 * 4 + 1], acc.y);
            atomicAdd(&sums[cur * DD + c4 * 4 + 2], acc.z);
            atomicAdd(&sums[cur * DD + c4 * 4 + 3], acc.w);
            if (c4 == 0) atomicAdd(&cnts[cur], cnt);
            acc = make_float4(0.f, 0.f, 0.f, 0.f);
            cnt = 0; cur = g;
        }
        float4 v = *(const float4*)&h[(size_t)r * DD + c4 * 4];
        acc.x += v.x; acc.y += v.y; acc.z += v.z; acc.w += v.w;
        ++cnt;
    }
    atomicAdd(&sums[cur * DD + c4 * 4 + 0], acc.x);
    atomicAdd(&sums[cur * DD + c4 * 4 + 1], acc.y);
    atomicAdd(&sums[cur * DD + c4 * 4 + 2], acc.z);
    atomicAdd(&sums[cur * DD + c4 * 4 + 3], acc.w);
    if (c4 == 0) atomicAdd(&cnts[cur], cnt);
}

__global__ void finalize_kernel(const float* __restrict__ sums, const int* __restrict__ cnts,
                                float* __restrict__ out)
{
    int g = blockIdx.x, c = threadIdx.x;
    out[g * DD + c] = sums[g * DD + c] / fmaxf((float)cnts[g], 1.f);
}

extern "C" void kernel_launch(void* const* d_in, const int* in_sizes, int n_in,
                              void* d_out, int out_size, void* d_ws, size_t ws_size,
                              hipStream_t stream)
{
    const float* x     = (const float*)d_in[0];
    const float* emb_W = (const float*)d_in[1];
    const float* Wqk   = (const float*)d_in[2];
    const float* Wv    = (const float*)d_in[3];
    const float* Wo    = (const float*)d_in[4];
    const float* bo    = (const float*)d_in[5];
    const float* W1    = (const float*)d_in[6];
    const float* b1    = (const float*)d_in[7];
    const float* W2    = (const float*)d_in[8];
    const float* b2    = (const float*)d_in[9];
    const int* eidx    = (const int*)d_in[10];
    const int* batch   = (const int*)d_in[11];
    float* out = (float*)d_out;

    char* base = (char*)d_ws;
    size_t off = 0;
    auto alloc = [&](size_t bytes) { char* p = base + off; off = (off + bytes + 255) & ~(size_t)255; return p; };

    float*          h    = (float*)alloc((size_t)NPAD * DD * 4);
    unsigned short* hc   = (unsigned short*)alloc((size_t)NPAD * 2 * DD * 2);
    char*           regB = alloc((size_t)NPAD * 2 * FFD * 2);
    unsigned short* xc   = (unsigned short*)regB;                                // phase 0
    unsigned short* QKVb = (unsigned short*)regB;                                // per-layer ph 1
    unsigned short* ac   = (unsigned short*)(regB + (size_t)NPAD * 384 * 2);     // per-layer ph 2
    unsigned short* fc   = (unsigned short*)regB;                                // per-layer ph 3

    unsigned short* WqkvT = (unsigned short*)alloc((size_t)LL * 384 * 256 * 2);
    unsigned short* WoT   = (unsigned short*)alloc((size_t)LL * 128 * 256 * 2);
    unsigned short* W1T   = (unsigned short*)alloc((size_t)LL * 512 * 256 * 2);
    unsigned short* W2T   = (unsigned short*)alloc((size_t)LL * 128 * 1024 * 2);
    unsigned short* embT  = (unsigned short*)alloc((size_t)128 * 256 * 2);

    int* counts  = (int*)alloc((NN + 1) * 4);
    int* offsets = (int*)alloc((NN + 1) * 4);
    int* cursor  = (int*)alloc(NN * 4);
    int* bsums   = (int*)alloc(64 * 4);
    int* csr_src = (int*)alloc((size_t)EE * 4);
    float* sums  = (float*)alloc(GG * DD * 4 + GG * 4);
    int* cnts    = (int*)(sums + GG * DD);

    const int* src = eidx;
    const int* dst = eidx + EE;

    hipMemsetAsync(counts, 0, (NN + 1) * sizeof(int), stream);
    hipMemsetAsync(cursor, 0, NN * sizeof(int), stream);
    hipMemsetAsync(sums, 0, GG * DD * sizeof(float) + GG * sizeof(int), stream);

    const int NB1 = (NN + 1023) / 1024;   // 49
    count_kernel<<<dim3((EE + 255) / 256), dim3(256), 0, stream>>>(dst, counts);
    scan1_kernel<<<dim3(NB1), dim3(1024), 0, stream>>>(counts, offsets, bsums);
    scan2_kernel<<<dim3(1), dim3(64), 0, stream>>>(bsums, NB1);
    scan3_kernel<<<dim3(NB1), dim3(1024), 0, stream>>>(offsets, bsums);
    fill_kernel<<<dim3((EE + 255) / 256), dim3(256), 0, stream>>>(src, dst, offsets, cursor, csr_src);

    WDescs ds;
    int b = 0, di = 0;
    auto addw = [&](const float* W, unsigned short* Wt, int K, int nkpad, int M) {
        ds.d[di].W = W; ds.d[di].Wt = Wt; ds.d[di].K = K;
        ds.d[di].nkpad = nkpad; ds.d[di].M = M; ds.d[di].base = b;
        b += M * nkpad; ++di;
    };
    addw(emb_W, embT, IN_DIM, 4, DD);
    for (int l = 0; l < LL; ++l) {
        addw(Wqk + (size_t)l * DD * 256, WqkvT + (size_t)l * 384 * 256, DD, 4, 256);
        addw(Wv  + (size_t)l * DD * DD,  WqkvT + (size_t)l * 384 * 256 + 256 * 256, DD, 4, 128);
        addw(Wo  + (size_t)l * DD * DD,  WoT + (size_t)l * 128 * 256, DD, 4, 128);
        addw(W1  + (size_t)l * DD * FFD, W1T + (size_t)l * 512 * 256, DD, 4, 512);
        addw(W2  + (size_t)l * FFD * DD, W2T + (size_t)l * 128 * 1024, FFD, 16, 128);
    }
    ds.n = di; ds.total = b;   // di == 16
    wcvt_all_kernel<<<dim3((b + 255) / 256), dim3(256), 0, stream>>>(ds);

    cvt_x_kernel<<<dim3((NN * 128 + 255) / 256), dim3(256), 0, stream>>>(x, xc);

    dim3 blk(256);
    const int gx = (NN + 127) / 128;   // 391

    // emb: h = x @ emb_W  (fp32 h + hi/lo hc)
    mfma_gemm<<<dim3(gx, 1), blk, 0, stream>>>(
        xc, embT, nullptr, nullptr, h, hc, nullptr, NN, 4, DD, 0);

    for (int l = 0; l < LL; ++l) {
        // QKV = h @ [Wqk|Wv] -> plain bf16 [n][384]
        mfma_gemm<<<dim3(gx, 3), blk, 0, stream>>>(
            hc, WqkvT + (size_t)l * 384 * 256, nullptr, nullptr,
            nullptr, nullptr, QKVb, NN, 4, 384, 0);
        attn_kernel<<<dim3(NN / 4), blk, 0, stream>>>(QKVb, offsets, csr_src, ac);
        // h = h + ac @ Wo + bo  (fp32 h + hi/lo hc)
        mfma_gemm<<<dim3(gx, 1), blk, 0, stream>>>(
            ac, WoT + (size_t)l * 128 * 256, bo + (size_t)l * DD, h,
            h, hc, nullptr, NN, 4, DD, 0);
        // fc = relu(h @ W1 + b1)  (hi/lo only)
        mfma_gemm<<<dim3(gx, 4), blk, 0, stream>>>(
            hc, W1T + (size_t)l * 512 * 256, b1 + (size_t)l * FFD, nullptr,
            nullptr, fc, nullptr, NN, 4, FFD, 1);
        // h = h + fc @ W2 + b2  (fp32 h + hi/lo hc)
        mfma_gemm<<<dim3(gx, 1), blk, 0, stream>>>(
            fc, W2T + (size_t)l * 128 * 1024, b2 + (size_t)l * DD, h,
            h, hc, nullptr, NN, 16, DD, 0);
    }

    pool_kernel<<<dim3((NN + 255) / 256), blk, 0, stream>>>(h, batch, sums, cnts);
    finalize_kernel<<<dim3(GG), dim3(128), 0, stream>>>(sums, cnts, out);
}

// Round 5
// 1000.553 us; speedup vs baseline: 2.4424x; 1.1166x over previous
//
#include <hip/hip_runtime.h>
#include <math.h>

#define NN 50000
#define NPAD 50048           // 391*128
#define IN_DIM 100
#define DD 128
#define HH 8
#define LL 3
#define GG 64
#define FFD 512
#define EE 800000

typedef __attribute__((ext_vector_type(8))) short bf8_t;   // 8 bf16 (4 VGPRs)
typedef __attribute__((ext_vector_type(4))) float f4_t;    // 4 fp32 acc

static __device__ __forceinline__ unsigned short f2bf(float f) {
    unsigned u = __builtin_bit_cast(unsigned, f);
    unsigned r = (u + 0x7FFFu + ((u >> 16) & 1u)) >> 16;
    return (unsigned short)r;
}
static __device__ __forceinline__ float bf2f(unsigned short b) {
    unsigned u = ((unsigned)b) << 16;
    return __builtin_bit_cast(float, u);
}

#define GLD16(gsrc, ldst) __builtin_amdgcn_global_load_lds( \
    (const __attribute__((address_space(1))) unsigned int*)(gsrc), \
    (__attribute__((address_space(3))) unsigned int*)(ldst), 16, 0, 0)

// ---------------------------------------------------------------------------
// Split-bf16 MFMA GEMM: C[n,M] = A[n,K] @ W[K,M] via hi/lo decomposition.
// Ac: [n][nk][2][32] bf16; Bc: [M][nk][2][32] bf16 (transposed+split weights)
// 128x128 tile, BK=32, 4 waves (2x2), 16x16x32 MFMA, 3 mfma/frag (Markidis).
// ---------------------------------------------------------------------------
__global__ __launch_bounds__(256) void mfma_gemm(
    const unsigned short* __restrict__ Ac,
    const unsigned short* __restrict__ Bc,
    const float* __restrict__ bias,
    const float* __restrict__ resid,
    float* __restrict__ Cf,
    unsigned short* __restrict__ Chl,
    unsigned short* __restrict__ Cb,
    int n, int nk, int M, int do_relu)
{
    __shared__ unsigned short ldsA[128 * 64];
    __shared__ unsigned short ldsB[128 * 64];
    const int tid = threadIdx.x;
    const int lane = tid & 63;
    const int wid = tid >> 6;
    const int wr = (wid >> 1) * 64;
    const int wc = (wid & 1) * 64;
    const long brow = (long)blockIdx.x * 128;
    const long bcol = (long)blockIdx.y * 128;

    f4_t acc[4][4] = {};

    const int srow = tid >> 3;
    const int kbg = (((tid & 7) << 4) ^ ((srow & 7) << 4)) >> 1;

    for (int kc = 0; kc < nk; ++kc) {
#pragma unroll
        for (int i = 0; i < 4; ++i) {
            int row = i * 32 + srow;
            const unsigned short* sA = Ac + ((brow + row) * (size_t)nk + kc) * 64 + kbg;
            GLD16(sA, &ldsA[((size_t)i * 256 + tid) * 8]);
            const unsigned short* sB = Bc + ((bcol + row) * (size_t)nk + kc) * 64 + kbg;
            GLD16(sB, &ldsB[((size_t)i * 256 + tid) * 8]);
        }
        __syncthreads();

        bf8_t ah[4], al[4], bh[4], bl[4];
        const int fr = lane & 15;
        const int kq = (lane >> 4) << 4;
#pragma unroll
        for (int m = 0; m < 4; ++m) {
            int row = wr + m * 16 + fr;
            int sw = (row & 7) << 4;
            ah[m] = *(const bf8_t*)&ldsA[row * 64 + ((kq ^ sw) >> 1)];
            al[m] = *(const bf8_t*)&ldsA[row * 64 + (((kq + 64) ^ sw) >> 1)];
        }
#pragma unroll
        for (int nn = 0; nn < 4; ++nn) {
            int row = wc + nn * 16 + fr;
            int sw = (row & 7) << 4;
            bh[nn] = *(const bf8_t*)&ldsB[row * 64 + ((kq ^ sw) >> 1)];
            bl[nn] = *(const bf8_t*)&ldsB[row * 64 + (((kq + 64) ^ sw) >> 1)];
        }
#pragma unroll
        for (int m = 0; m < 4; ++m)
#pragma unroll
            for (int nn = 0; nn < 4; ++nn) {
                acc[m][nn] = __builtin_amdgcn_mfma_f32_16x16x32_bf16(ah[m], bh[nn], acc[m][nn], 0, 0, 0);
                acc[m][nn] = __builtin_amdgcn_mfma_f32_16x16x32_bf16(al[m], bh[nn], acc[m][nn], 0, 0, 0);
                acc[m][nn] = __builtin_amdgcn_mfma_f32_16x16x32_bf16(ah[m], bl[nn], acc[m][nn], 0, 0, 0);
            }
        __syncthreads();
    }

    const int efr = lane & 15, efq = lane >> 4;
#pragma unroll
    for (int m = 0; m < 4; ++m) {
#pragma unroll
        for (int i = 0; i < 4; ++i) {
            long row = brow + wr + m * 16 + efq * 4 + i;
            if (row >= n) continue;
#pragma unroll
            for (int nn = 0; nn < 4; ++nn) {
                int col = (int)bcol + wc + nn * 16 + efr;
                float v = acc[m][nn][i];
                if (bias) v += bias[col];
                if (do_relu) v = fmaxf(v, 0.f);
                if (resid) v += resid[row * M + col];
                if (Cf) Cf[row * M + col] = v;
                if (Cb) Cb[row * M + col] = f2bf(v);
                if (Chl) {
                    unsigned short hb = f2bf(v);
                    float lo = v - bf2f(hb);
                    size_t cb = (row * (size_t)(M >> 5) + (col >> 5)) * 64 + (col & 31);
                    Chl[cb] = hb;
                    Chl[cb + 32] = f2bf(lo);
                }
            }
        }
    }
}

// ---------------------------------------------------------------------------
// Fused FF: h = h + relu(h@W1 + b1)@W2 + b2 (per 128-row block, fc in LDS).
// Step1: mid = relu(hc@W1[:,c*128..]) 3-mfma split -> LDS bf16 (swizzled).
// Step2: acc2 += mid@W2[c*128..,:], 2-mfma split (A plain bf16, B hi/lo).
// ---------------------------------------------------------------------------
__global__ __launch_bounds__(256) void ff_fused(
    const unsigned short* __restrict__ hcin,   // [NPAD][4][2][32]
    const unsigned short* __restrict__ W1T,    // [512][4][2][32]
    const unsigned short* __restrict__ W2T,    // [128][16][2][32]
    const float* __restrict__ b1,              // [512]
    const float* __restrict__ b2,              // [128]
    float* __restrict__ h,                     // [NPAD][128] resid in/out
    unsigned short* __restrict__ hcout,        // [NPAD][4][2][32] (== hcin)
    int n)
{
    __shared__ unsigned short ldsA[128 * 64];   // 16 KB
    __shared__ unsigned short ldsB[128 * 64];   // 16 KB
    __shared__ unsigned short midb[128 * 128];  // 32 KB, bf16, XOR-swizzled
    const int tid = threadIdx.x;
    const int lane = tid & 63;
    const int wid = tid >> 6;
    const int wr = (wid >> 1) * 64;
    const int wc = (wid & 1) * 64;
    const long brow = (long)blockIdx.x * 128;

    const int srow = tid >> 3;
    const int kbg = (((tid & 7) << 4) ^ ((srow & 7) << 4)) >> 1;
    const int fr = lane & 15;
    const int kq = (lane >> 4) << 4;           // k-group byte offset
    const int efr = lane & 15, efq = lane >> 4;

    f4_t acc2[4][4] = {};

    for (int c = 0; c < 4; ++c) {
        // ---- step 1: mid = relu(hc @ W1 chunk + b1) ----
        f4_t acc1[4][4] = {};
        for (int kc = 0; kc < 4; ++kc) {
#pragma unroll
            for (int i = 0; i < 4; ++i) {
                int row = i * 32 + srow;
                GLD16(hcin + ((brow + row) * (size_t)4 + kc) * 64 + kbg,
                      &ldsA[((size_t)i * 256 + tid) * 8]);
                GLD16(W1T + (((size_t)c * 128 + row) * 4 + kc) * 64 + kbg,
                      &ldsB[((size_t)i * 256 + tid) * 8]);
            }
            __syncthreads();
            bf8_t ah[4], al[4], bh[4], bl[4];
#pragma unroll
            for (int m = 0; m < 4; ++m) {
                int row = wr + m * 16 + fr;
                int sw = (row & 7) << 4;
                ah[m] = *(const bf8_t*)&ldsA[row * 64 + ((kq ^ sw) >> 1)];
                al[m] = *(const bf8_t*)&ldsA[row * 64 + (((kq + 64) ^ sw) >> 1)];
            }
#pragma unroll
            for (int nn = 0; nn < 4; ++nn) {
                int row = wc + nn * 16 + fr;
                int sw = (row & 7) << 4;
                bh[nn] = *(const bf8_t*)&ldsB[row * 64 + ((kq ^ sw) >> 1)];
                bl[nn] = *(const bf8_t*)&ldsB[row * 64 + (((kq + 64) ^ sw) >> 1)];
            }
#pragma unroll
            for (int m = 0; m < 4; ++m)
#pragma unroll
                for (int nn = 0; nn < 4; ++nn) {
                    acc1[m][nn] = __builtin_amdgcn_mfma_f32_16x16x32_bf16(ah[m], bh[nn], acc1[m][nn], 0, 0, 0);
                    acc1[m][nn] = __builtin_amdgcn_mfma_f32_16x16x32_bf16(al[m], bh[nn], acc1[m][nn], 0, 0, 0);
                    acc1[m][nn] = __builtin_amdgcn_mfma_f32_16x16x32_bf16(ah[m], bl[nn], acc1[m][nn], 0, 0, 0);
                }
            __syncthreads();
        }
        // epilogue 1: relu(+b1) -> midb (bf16, byte-swizzled ^((row&7)<<4))
#pragma unroll
        for (int m = 0; m < 4; ++m)
#pragma unroll
            for (int i = 0; i < 4; ++i) {
                int lrow = wr + m * 16 + efq * 4 + i;
#pragma unroll
                for (int nn = 0; nn < 4; ++nn) {
                    int col = wc + nn * 16 + efr;
                    float v = fmaxf(acc1[m][nn][i] + b1[c * 128 + col], 0.f);
                    int e = (lrow << 7) + ((((col << 1) ^ ((lrow & 7) << 4))) >> 1);
                    midb[e] = f2bf(v);
                }
            }
        __syncthreads();
        // ---- step 2: acc2 += mid @ W2[c*128..(c+1)*128, :] ----
        for (int kq2 = 0; kq2 < 4; ++kq2) {
            int kcp = c * 4 + kq2;
#pragma unroll
            for (int i = 0; i < 4; ++i) {
                int row = i * 32 + srow;
                GLD16(W2T + ((size_t)row * 16 + kcp) * 64 + kbg,
                      &ldsB[((size_t)i * 256 + tid) * 8]);
            }
            __syncthreads();
            bf8_t am[4], bh2[4], bl2[4];
#pragma unroll
            for (int m = 0; m < 4; ++m) {
                int lrow = wr + m * 16 + fr;
                int kbyte = (kq2 * 64 + kq) ^ ((lrow & 7) << 4);
                am[m] = *(const bf8_t*)&midb[(lrow << 7) + (kbyte >> 1)];
            }
#pragma unroll
            for (int nn = 0; nn < 4; ++nn) {
                int row = wc + nn * 16 + fr;
                int sw = (row & 7) << 4;
                bh2[nn] = *(const bf8_t*)&ldsB[row * 64 + ((kq ^ sw) >> 1)];
                bl2[nn] = *(const bf8_t*)&ldsB[row * 64 + (((kq + 64) ^ sw) >> 1)];
            }
#pragma unroll
            for (int m = 0; m < 4; ++m)
#pragma unroll
                for (int nn = 0; nn < 4; ++nn) {
                    acc2[m][nn] = __builtin_amdgcn_mfma_f32_16x16x32_bf16(am[m], bh2[nn], acc2[m][nn], 0, 0, 0);
                    acc2[m][nn] = __builtin_amdgcn_mfma_f32_16x16x32_bf16(am[m], bl2[nn], acc2[m][nn], 0, 0, 0);
                }
            __syncthreads();
        }
    }

    // epilogue 2: h += ff + b2 ; rewrite h fp32 + hc hi/lo
#pragma unroll
    for (int m = 0; m < 4; ++m)
#pragma unroll
        for (int i = 0; i < 4; ++i) {
            long row = brow + wr + m * 16 + efq * 4 + i;
            if (row >= n) continue;
#pragma unroll
            for (int nn = 0; nn < 4; ++nn) {
                int col = wc + nn * 16 + efr;
                float v = acc2[m][nn][i] + b2[col] + h[row * 128 + col];
                h[row * 128 + col] = v;
                unsigned short hb = f2bf(v);
                size_t cb = (row * (size_t)4 + (col >> 5)) * 64 + (col & 31);
                hcout[cb] = hb;
                hcout[cb + 32] = f2bf(v - bf2f(hb));
            }
        }
}

__global__ void cvt_x_kernel(const float* __restrict__ x, unsigned short* __restrict__ xc)
{
    int idx = blockIdx.x * 256 + threadIdx.x;
    if (idx >= NN * 128) return;
    int node = idx >> 7, col = idx & 127;
    float v = (col < IN_DIM) ? x[(size_t)node * IN_DIM + col] : 0.f;
    unsigned short hb = f2bf(v);
    float lo = v - bf2f(hb);
    size_t b = (size_t)node * 256 + (col >> 5) * 64 + (col & 31);
    xc[b] = hb;
    xc[b + 32] = f2bf(lo);
}

// 16 weight matrices: 1 emb + (Wqk, Wv, Wo, W1, W2) x 3 layers
struct WDesc { const float* W; unsigned short* Wt; int K, nkpad, M, base; };
struct WDescs { WDesc d[16]; int n; int total; };

__global__ void wcvt_all_kernel(WDescs ds)
{
    int idx = blockIdx.x * 256 + threadIdx.x;
    if (idx >= ds.total) return;
    int di = 0;
    while (di + 1 < ds.n && idx >= ds.d[di + 1].base) ++di;
    WDesc w = ds.d[di];
    int loc = idx - w.base;
    int m = loc % w.M;
    int kc = loc / w.M;
    size_t ob = ((size_t)m * w.nkpad + kc) * 64;
    for (int i = 0; i < 32; ++i) {
        int k = kc * 32 + i;
        float v = (k < w.K) ? w.W[(size_t)k * w.M + m] : 0.f;
        unsigned short hb = f2bf(v);
        w.Wt[ob + i] = hb;
        w.Wt[ob + 32 + i] = f2bf(v - bf2f(hb));
    }
}

__global__ void count_kernel(const int* __restrict__ dst, int* __restrict__ counts)
{
    int e = blockIdx.x * 256 + threadIdx.x;
    if (e < EE) atomicAdd(&counts[dst[e]], 1);
}

__global__ __launch_bounds__(1024) void scan1_kernel(
    const int* __restrict__ counts, int* __restrict__ offsets, int* __restrict__ bsums)
{
    __shared__ int buf[1024];
    int tid = threadIdx.x;
    int i = blockIdx.x * 1024 + tid;
    int v = (i < NN) ? counts[i] : 0;
    buf[tid] = v;
    __syncthreads();
    for (int off = 1; off < 1024; off <<= 1) {
        int t = (tid >= off) ? buf[tid - off] : 0;
        __syncthreads();
        buf[tid] += t;
        __syncthreads();
    }
    if (i < NN) offsets[i + 1] = buf[tid];
    if (tid == 1023) bsums[blockIdx.x] = buf[1023];
}

__global__ void scan2_kernel(int* __restrict__ bsums, int nb)
{
    __shared__ int buf[64];
    int tid = threadIdx.x;
    int v = (tid < nb) ? bsums[tid] : 0;
    buf[tid] = v;
    __syncthreads();
    for (int off = 1; off < 64; off <<= 1) {
        int t = (tid >= off) ? buf[tid - off] : 0;
        __syncthreads();
        buf[tid] += t;
        __syncthreads();
    }
    if (tid < nb) bsums[tid] = buf[tid] - v;   // exclusive
}

__global__ __launch_bounds__(1024) void scan3_kernel(
    int* __restrict__ offsets, const int* __restrict__ bsums)
{
    int i = blockIdx.x * 1024 + threadIdx.x;
    if (i < NN) offsets[i + 1] += bsums[blockIdx.x];
    if (i == 0) offsets[0] = 0;
}

__global__ void fill_kernel(const int* __restrict__ src, const int* __restrict__ dst,
                            const int* __restrict__ offsets, int* __restrict__ cursor,
                            int* __restrict__ csr_src)
{
    int e = blockIdx.x * 256 + threadIdx.x;
    if (e < EE) {
        int d = dst[e];
        int pos = atomicAdd(&cursor[d], 1);
        csr_src[offsets[d] + pos] = src[e];
    }
}

// ---------------------------------------------------------------------------
// Fused attention: one wave per dst node; 8 heads x 8 lanes (2 dims/lane).
// QKV plain bf16 [n][384] (q|k|v). Online softmax, 2-edge unrolled.
// ---------------------------------------------------------------------------
__global__ __launch_bounds__(256) void attn_kernel(
    const unsigned short* __restrict__ QKV,
    const int* __restrict__ offsets, const int* __restrict__ csr_src,
    unsigned short* __restrict__ ac)    // [n][4][2][32] hi/lo
{
    int wave = threadIdx.x >> 6;
    int lane = threadIdx.x & 63;
    int node = blockIdx.x * 4 + wave;
    if (node >= NN) return;
    int qoff = ((lane >> 3) << 4) + ((lane & 7) << 1);
    ushort2 k2 = *(const ushort2*)&QKV[(size_t)node * 384 + 128 + qoff];
    float kx = bf2f(k2.x), ky = bf2f(k2.y);
    float m = -INFINITY, s = 0.f, a0 = 0.f, a1 = 0.f;
    int e = offsets[node], end = offsets[node + 1];
    for (; e + 1 < end; e += 2) {
        int j0 = csr_src[e], j1 = csr_src[e + 1];
        ushort2 q0 = *(const ushort2*)&QKV[(size_t)j0 * 384 + qoff];
        ushort2 v0 = *(const ushort2*)&QKV[(size_t)j0 * 384 + 256 + qoff];
        ushort2 q1 = *(const ushort2*)&QKV[(size_t)j1 * 384 + qoff];
        ushort2 v1 = *(const ushort2*)&QKV[(size_t)j1 * 384 + 256 + qoff];
        float p0 = kx * bf2f(q0.x) + ky * bf2f(q0.y);
        float p1 = kx * bf2f(q1.x) + ky * bf2f(q1.y);
        p0 += __shfl_xor(p0, 1, 64);
        p0 += __shfl_xor(p0, 2, 64);
        p0 += __shfl_xor(p0, 4, 64);
        p1 += __shfl_xor(p1, 1, 64);
        p1 += __shfl_xor(p1, 2, 64);
        p1 += __shfl_xor(p1, 4, 64);
        float sc0 = p0 * 0.25f, sc1 = p1 * 0.25f;
        float mn = fmaxf(m, fmaxf(sc0, sc1));
        float corr = __expf(m - mn);
        float w0 = __expf(sc0 - mn), w1 = __expf(sc1 - mn);
        s  = s  * corr + w0 + w1;
        a0 = a0 * corr + w0 * bf2f(v0.x) + w1 * bf2f(v1.x);
        a1 = a1 * corr + w0 * bf2f(v0.y) + w1 * bf2f(v1.y);
        m = mn;
    }
    if (e < end) {
        int j = csr_src[e];
        ushort2 qj = *(const ushort2*)&QKV[(size_t)j * 384 + qoff];
        ushort2 vj = *(const ushort2*)&QKV[(size_t)j * 384 + 256 + qoff];
        float p = kx * bf2f(qj.x) + ky * bf2f(qj.y);
        p += __shfl_xor(p, 1, 64);
        p += __shfl_xor(p, 2, 64);
        p += __shfl_xor(p, 4, 64);
        float score = p * 0.25f;
        float mn = fmaxf(m, score);
        float corr = __expf(m - mn);
        float w = __expf(score - mn);
        s  = s  * corr + w;
        a0 = a0 * corr + w * bf2f(vj.x);
        a1 = a1 * corr + w * bf2f(vj.y);
        m = mn;
    }
    float inv = 1.f / (s + 1e-16f);
    float o0 = a0 * inv, o1 = a1 * inv;
    int chunk = qoff >> 5, pos = qoff & 31;
    size_t b = ((size_t)node * 4 + chunk) * 64 + pos;
    unsigned short h0 = f2bf(o0), h1 = f2bf(o1);
    ac[b] = h0;       ac[b + 1] = h1;
    ac[b + 32] = f2bf(o0 - bf2f(h0));
    ac[b + 33] = f2bf(o1 - bf2f(h1));
}

// ---------------------------------------------------------------------------
// Mean pool per graph: 256 rows/block striped 8 ways, float4 cols
// ---------------------------------------------------------------------------
__global__ __launch_bounds__(256) void pool_kernel(
    const float* __restrict__ h, const int* __restrict__ batch,
    float* __restrict__ sums, int* __restrict__ cnts)
{
    int tid = threadIdx.x;
    int c4 = tid & 31;
    int rs = tid >> 5;
    int start = blockIdx.x * 256;
    int r0 = start + rs;
    if (r0 >= NN) return;
    int lim = min(start + 256, NN);
    float4 acc = make_float4(0.f, 0.f, 0.f, 0.f);
    int cnt = 0;
    int cur = batch[r0];
    for (int r = r0; r < lim; r += 8) {
        int g = batch[r];
        if (g != cur) {
            atomicAdd(&sums[cur * DD + c4 * 4 + 0], acc.x);
            atomicAdd(&sums[cur * DD + c4 * 4 + 1], acc.y);
            atomicAdd(&sums[cur * DD + c4 * 4 + 2], acc.z);
            atomicAdd(&sums[cur * DD + c4 * 4 + 3], acc.w);
            if (c4 == 0) atomicAdd(&cnts[cur], cnt);
            acc = make_float4(0.f, 0.f, 0.f, 0.f);
            cnt = 0; cur = g;
        }
        float4 v = *(const float4*)&h[(size_t)r * DD + c4 * 4];
        acc.x += v.x; acc.y += v.y; acc.z += v.z; acc.w += v.w;
        ++cnt;
    }
    atomicAdd(&sums[cur * DD + c4 * 4 + 0], acc.x);
    atomicAdd(&sums[cur * DD + c4 * 4 + 1], acc.y);
    atomicAdd(&sums[cur * DD + c4 * 4 + 2], acc.z);
    atomicAdd(&sums[cur * DD + c4 * 4 + 3], acc.w);
    if (c4 == 0) atomicAdd(&cnts[cur], cnt);
}

__global__ void finalize_kernel(const float* __restrict__ sums, const int* __restrict__ cnts,
                                float* __restrict__ out)
{
    int g = blockIdx.x, c = threadIdx.x;
    out[g * DD + c] = sums[g * DD + c] / fmaxf((float)cnts[g], 1.f);
}

extern "C" void kernel_launch(void* const* d_in, const int* in_sizes, int n_in,
                              void* d_out, int out_size, void* d_ws, size_t ws_size,
                              hipStream_t stream)
{
    const float* x     = (const float*)d_in[0];
    const float* emb_W = (const float*)d_in[1];
    const float* Wqk   = (const float*)d_in[2];
    const float* Wv    = (const float*)d_in[3];
    const float* Wo    = (const float*)d_in[4];
    const float* bo    = (const float*)d_in[5];
    const float* W1    = (const float*)d_in[6];
    const float* b1    = (const float*)d_in[7];
    const float* W2    = (const float*)d_in[8];
    const float* b2    = (const float*)d_in[9];
    const int* eidx    = (const int*)d_in[10];
    const int* batch   = (const int*)d_in[11];
    float* out = (float*)d_out;

    char* base = (char*)d_ws;
    size_t off = 0;
    auto alloc = [&](size_t bytes) { char* p = base + off; off = (off + bytes + 255) & ~(size_t)255; return p; };

    float*          h    = (float*)alloc((size_t)NPAD * DD * 4);
    unsigned short* hc   = (unsigned short*)alloc((size_t)NPAD * 2 * DD * 2);
    char*           regB = alloc((size_t)NPAD * 384 * 2 + (size_t)NPAD * 256 * 2 + 256);
    unsigned short* xc   = (unsigned short*)regB;                                // phase 0
    unsigned short* QKVb = (unsigned short*)regB;                                // per-layer ph 1
    unsigned short* ac   = (unsigned short*)(regB + (size_t)NPAD * 384 * 2);     // per-layer ph 2

    unsigned short* WqkvT = (unsigned short*)alloc((size_t)LL * 384 * 256 * 2);
    unsigned short* WoT   = (unsigned short*)alloc((size_t)LL * 128 * 256 * 2);
    unsigned short* W1T   = (unsigned short*)alloc((size_t)LL * 512 * 256 * 2);
    unsigned short* W2T   = (unsigned short*)alloc((size_t)LL * 128 * 1024 * 2);
    unsigned short* embT  = (unsigned short*)alloc((size_t)128 * 256 * 2);

    int* counts  = (int*)alloc((NN + 1) * 4);
    int* offsets = (int*)alloc((NN + 1) * 4);
    int* cursor  = (int*)alloc(NN * 4);
    int* bsums   = (int*)alloc(64 * 4);
    int* csr_src = (int*)alloc((size_t)EE * 4);
    float* sums  = (float*)alloc(GG * DD * 4 + GG * 4);
    int* cnts    = (int*)(sums + GG * DD);

    const int* src = eidx;
    const int* dst = eidx + EE;

    hipMemsetAsync(counts, 0, (NN + 1) * sizeof(int), stream);
    hipMemsetAsync(cursor, 0, NN * sizeof(int), stream);
    hipMemsetAsync(sums, 0, GG * DD * sizeof(float) + GG * sizeof(int), stream);

    const int NB1 = (NN + 1023) / 1024;   // 49
    count_kernel<<<dim3((EE + 255) / 256), dim3(256), 0, stream>>>(dst, counts);
    scan1_kernel<<<dim3(NB1), dim3(1024), 0, stream>>>(counts, offsets, bsums);
    scan2_kernel<<<dim3(1), dim3(64), 0, stream>>>(bsums, NB1);
    scan3_kernel<<<dim3(NB1), dim3(1024), 0, stream>>>(offsets, bsums);
    fill_kernel<<<dim3((EE + 255) / 256), dim3(256), 0, stream>>>(src, dst, offsets, cursor, csr_src);

    WDescs ds;
    int b = 0, di = 0;
    auto addw = [&](const float* W, unsigned short* Wt, int K, int nkpad, int M) {
        ds.d[di].W = W; ds.d[di].Wt = Wt; ds.d[di].K = K;
        ds.d[di].nkpad = nkpad; ds.d[di].M = M; ds.d[di].base = b;
        b += M * nkpad; ++di;
    };
    addw(emb_W, embT, IN_DIM, 4, DD);
    for (int l = 0; l < LL; ++l) {
        addw(Wqk + (size_t)l * DD * 256, WqkvT + (size_t)l * 384 * 256, DD, 4, 256);
        addw(Wv  + (size_t)l * DD * DD,  WqkvT + (size_t)l * 384 * 256 + 256 * 256, DD, 4, 128);
        addw(Wo  + (size_t)l * DD * DD,  WoT + (size_t)l * 128 * 256, DD, 4, 128);
        addw(W1  + (size_t)l * DD * FFD, W1T + (size_t)l * 512 * 256, DD, 4, 512);
        addw(W2  + (size_t)l * FFD * DD, W2T + (size_t)l * 128 * 1024, FFD, 16, 128);
    }
    ds.n = di; ds.total = b;   // di == 16
    wcvt_all_kernel<<<dim3((b + 255) / 256), dim3(256), 0, stream>>>(ds);

    cvt_x_kernel<<<dim3((NN * 128 + 255) / 256), dim3(256), 0, stream>>>(x, xc);

    dim3 blk(256);
    const int gx = (NN + 127) / 128;   // 391

    // emb: h = x @ emb_W  (fp32 h + hi/lo hc)
    mfma_gemm<<<dim3(gx, 1), blk, 0, stream>>>(
        xc, embT, nullptr, nullptr, h, hc, nullptr, NN, 4, DD, 0);

    for (int l = 0; l < LL; ++l) {
        // QKV = h @ [Wqk|Wv] -> plain bf16 [n][384]
        mfma_gemm<<<dim3(gx, 3), blk, 0, stream>>>(
            hc, WqkvT + (size_t)l * 384 * 256, nullptr, nullptr,
            nullptr, nullptr, QKVb, NN, 4, 384, 0);
        attn_kernel<<<dim3(NN / 4), blk, 0, stream>>>(QKVb, offsets, csr_src, ac);
        // h = h + ac @ Wo + bo  (fp32 h + hi/lo hc)
        mfma_gemm<<<dim3(gx, 1), blk, 0, stream>>>(
            ac, WoT + (size_t)l * 128 * 256, bo + (size_t)l * DD, h,
            h, hc, nullptr, NN, 4, DD, 0);
        // h = h + relu(h@W1+b1)@W2 + b2  (fused, fc stays in LDS)
        ff_fused<<<dim3(gx), blk, 0, stream>>>(
            hc, W1T + (size_t)l * 512 * 256, W2T + (size_t)l * 128 * 1024,
            b1 + (size_t)l * FFD, b2 + (size_t)l * DD, h, hc, NN);
    }

    pool_kernel<<<dim3((NN + 255) / 256), blk, 0, stream>>>(h, batch, sums, cnts);
    finalize_kernel<<<dim3(GG), dim3(128), 0, stream>>>(sums, cnts, out);
}